// Round 1
// baseline (2831.512 us; speedup 1.0000x reference)
//
#include <hip/hip_runtime.h>
#include <hip/hip_bf16.h>

// Problem constants (hardcoded per reference: N=8192, D=H=1024, NSTEP=8)
#define NN 8192
#define HH 1024
#define NSTEP 8

// ---- workspace layout (float offsets) ----
#define OFF_ATTN   0                     // attn_feat [8192*1024]
#define OFF_HOP    8388608               // hop_feat  [8192*1024]
#define BASE2      16777216
#define OFF_NEG    (BASE2 + 0)           // [8192]
#define OFF_SEL    (BASE2 + 8192)        // [8192]
#define OFF_H      (BASE2 + 16384)       // h[parity][chain][1024]  (2*2*1024)
#define OFF_C      (BASE2 + 20480)       // c[parity][chain][1024]
#define OFF_X      (BASE2 + 24576)       // x[chain][1024]
#define OFF_G      (BASE2 + 26624)       // g[chain][4096]
#define OFF_QW     (BASE2 + 34816)       // qw[chain][1024]   (h @ hop_wq)
#define OFF_QW2    (BASE2 + 36864)       // qw2[chain][1024]  (q @ attn_wq)
#define OFF_Q      (BASE2 + 38912)       // q[chain][1024]    (glimpse output)
#define OFF_GPART  (BASE2 + 40960)       // glimpse partials [128][2][1028] {m,l,pad,pad,ctx[1024]}
#define OFF_CPART  (BASE2 + 304128)      // critic attn partials [128][1028]
#define OFF_AMAXV  (BASE2 + 435712)      // [128] block max score
#define OFF_AMAXI  (BASE2 + 435840)      // [128] block argmax (int bits)

#define NB_PASS 128                      // blocks for N-passes (glimpse / attn)

__device__ __forceinline__ float sigmoidf_(float x) {
    return 1.0f / (1.0f + __expf(-x));
}
__device__ __forceinline__ float tanhf_(float x) {
    // stable: 1 - 2/(e^{2x}+1); handles +-inf of expf gracefully
    float e = __expf(2.0f * x);
    return 1.0f - 2.0f / (e + 1.0f);
}

// ---------------- init: neg, sel, h/c parity-0, x inputs ----------------
__global__ __launch_bounds__(256) void k_init(const int* __restrict__ mask,
                                              const float* __restrict__ init_h,
                                              const float* __restrict__ init_c,
                                              const float* __restrict__ init_i,
                                              float* __restrict__ ws) {
    int i = blockIdx.x * 256 + threadIdx.x;
    if (i < NN) {
        ws[OFF_NEG + i] = (mask[i] == 0) ? -1e8f : 0.0f;
        ws[OFF_SEL + i] = 0.0f;
    }
    if (i < HH) {
        ws[OFF_H + i]        = init_h[i];   // parity0 chain0 (actor)
        ws[OFF_H + 1024 + i] = init_h[i];   // parity0 chain1 (critic)
        ws[OFF_C + i]        = init_c[i];
        ws[OFF_C + 1024 + i] = init_c[i];
        ws[OFF_X + i]        = init_i[i];
        ws[OFF_X + 1024 + i] = init_i[i];
    }
}

// ---------------- precompute GEMM: feats = enc @ {attn_wm, hop_wm} ----------------
// grid (16, 128, 2), block 256 (16x16 logical), 64x64 tile, 4x4 per thread
__global__ __launch_bounds__(256) void k_gemm(const float* __restrict__ A,
                                              const float* __restrict__ W0,
                                              const float* __restrict__ W1,
                                              float* __restrict__ ws) {
    const float* B = blockIdx.z ? W1 : W0;
    float* Cout = ws + (blockIdx.z ? OFF_HOP : OFF_ATTN);
    const int rowbase = blockIdx.y * 64;
    const int colbase = blockIdx.x * 64;
    __shared__ float As[16][68];  // As[k][m] (transposed)
    __shared__ float Bs[16][68];  // Bs[k][n]
    const int t  = threadIdx.x;
    const int tx = t & 15, ty = t >> 4;
    const int ar = t >> 2, ac4 = (t & 3) << 2;   // A staging: row, 4-k group
    const int bk = t >> 4, bc4 = (t & 15) << 2;  // B staging: k-row, 4-n group
    float acc[4][4] = {};
    for (int kk = 0; kk < 1024; kk += 16) {
        float4 a4 = *(const float4*)&A[(rowbase + ar) * 1024 + kk + ac4];
        float4 b4 = *(const float4*)&B[(kk + bk) * 1024 + colbase + bc4];
        __syncthreads();
        As[ac4 + 0][ar] = a4.x;
        As[ac4 + 1][ar] = a4.y;
        As[ac4 + 2][ar] = a4.z;
        As[ac4 + 3][ar] = a4.w;
        *(float4*)&Bs[bk][bc4] = b4;
        __syncthreads();
#pragma unroll
        for (int k = 0; k < 16; k++) {
            float4 av = *(const float4*)&As[k][ty * 4];
            float4 bv = *(const float4*)&Bs[k][tx * 4];
            acc[0][0] += av.x * bv.x; acc[0][1] += av.x * bv.y; acc[0][2] += av.x * bv.z; acc[0][3] += av.x * bv.w;
            acc[1][0] += av.y * bv.x; acc[1][1] += av.y * bv.y; acc[1][2] += av.y * bv.z; acc[1][3] += av.y * bv.w;
            acc[2][0] += av.z * bv.x; acc[2][1] += av.z * bv.y; acc[2][2] += av.z * bv.z; acc[2][3] += av.z * bv.w;
            acc[3][0] += av.w * bv.x; acc[3][1] += av.w * bv.y; acc[3][2] += av.w * bv.z; acc[3][3] += av.w * bv.w;
        }
    }
#pragma unroll
    for (int i = 0; i < 4; i++) {
        float4 o = make_float4(acc[i][0], acc[i][1], acc[i][2], acc[i][3]);
        *(float4*)&Cout[(rowbase + ty * 4 + i) * 1024 + colbase + tx * 4] = o;
    }
}

// ---------------- LSTM gates for both chains; also zeroes qw/qw2 ----------------
// grid 512, block 256: block handles 8 gate rows
__global__ __launch_bounds__(256) void k_lstm(const float* __restrict__ w_ih,
                                              const float* __restrict__ w_hh,
                                              const float* __restrict__ b_ih,
                                              const float* __restrict__ b_hh,
                                              float* __restrict__ ws, int parity) {
    const int t = threadIdx.x;
    if (blockIdx.x == 0) {
        for (int i = t; i < 4096; i += 256) ws[OFF_QW + i] = 0.0f;  // qw + qw2 contiguous
    }
    float4 xa = ((const float4*)(ws + OFF_X))[t];
    float4 xc = ((const float4*)(ws + OFF_X + 1024))[t];
    float4 ha = ((const float4*)(ws + OFF_H + parity * 2048))[t];
    float4 hc = ((const float4*)(ws + OFF_H + parity * 2048 + 1024))[t];
    __shared__ float lds[16];
    const int j0 = blockIdx.x * 8;
#pragma unroll
    for (int r = 0; r < 8; r++) {
        const int j = j0 + r;
        float4 wi = *(const float4*)&w_ih[j * 1024 + t * 4];
        float4 wh = *(const float4*)&w_hh[j * 1024 + t * 4];
        float pa = wi.x * xa.x + wi.y * xa.y + wi.z * xa.z + wi.w * xa.w
                 + wh.x * ha.x + wh.y * ha.y + wh.z * ha.z + wh.w * ha.w;
        float pc = wi.x * xc.x + wi.y * xc.y + wi.z * xc.z + wi.w * xc.w
                 + wh.x * hc.x + wh.y * hc.y + wh.z * hc.z + wh.w * hc.w;
        for (int off = 32; off; off >>= 1) {
            pa += __shfl_down(pa, off);
            pc += __shfl_down(pc, off);
        }
        if ((t & 63) == 0) { lds[t >> 6] = pa; lds[8 + (t >> 6)] = pc; }
        __syncthreads();
        if (t == 0) {
            float bb = b_ih[j] + b_hh[j];
            ws[OFF_G + j]        = lds[0] + lds[1] + lds[2] + lds[3] + bb;
            ws[OFF_G + 4096 + j] = lds[8] + lds[9] + lds[10] + lds[11] + bb;
        }
        __syncthreads();
    }
}

// ---------------- h,c update (persist to parity^1) + qw = h @ hop_wq ----------------
// grid (4 kblocks, 8 jchunks, 2 chains), block 256
__global__ __launch_bounds__(256) void k_hq(const float* __restrict__ hop_wq,
                                            float* __restrict__ ws, int parity) {
    const int kb = blockIdx.x, jc = blockIdx.y, cid = blockIdx.z;
    const int t = threadIdx.x;
    __shared__ float hloc[128];
    const float* g    = ws + OFF_G + cid * 4096;
    const float* cold = ws + OFF_C + parity * 2048 + cid * 1024;
    float* hnew = ws + OFF_H + (parity ^ 1) * 2048 + cid * 1024;
    float* cnew = ws + OFF_C + (parity ^ 1) * 2048 + cid * 1024;
    const int j0 = jc * 128;
    if (t < 128) {
        const int j = j0 + t;
        float ig = sigmoidf_(g[j]);
        float fg = sigmoidf_(g[1024 + j]);
        float gg = tanhf_(g[2048 + j]);
        float og = sigmoidf_(g[3072 + j]);
        float cv = fg * cold[j] + ig * gg;
        float hv = og * tanhf_(cv);
        hloc[t] = hv;
        if (kb == 0) { hnew[j] = hv; cnew[j] = cv; }
    }
    __syncthreads();
    const int k = kb * 256 + t;
    float acc = 0.0f;
#pragma unroll 8
    for (int jj = 0; jj < 128; jj++) acc += hloc[jj] * hop_wq[(j0 + jj) * 1024 + k];
    atomicAdd(&ws[OFF_QW + cid * 1024 + k], acc);
}

// ---------------- glimpse: one-pass online-softmax context over hop_feat (both chains) ----------------
// grid NB_PASS, block 256
__global__ __launch_bounds__(256) void k_glimpse(const float* __restrict__ hop_v,
                                                 float* __restrict__ ws) {
    const int t = threadIdx.x, b = blockIdx.x;
    float4 qa = *(const float4*)&ws[OFF_QW + t * 4];
    float4 qc = *(const float4*)&ws[OFF_QW + 1024 + t * 4];
    float4 v4 = *(const float4*)&hop_v[t * 4];
    const float* hop = ws + OFF_HOP;
    float ma = -1e30f, la = 0.0f, mc = -1e30f, lc = 0.0f;
    float4 ca = make_float4(0, 0, 0, 0), cc = make_float4(0, 0, 0, 0);
    __shared__ float lds[32];
    for (int i = b; i < NN; i += NB_PASS) {
        float4 f = *(const float4*)&hop[i * 1024 + t * 4];
        float sa = tanhf_(f.x + qa.x) * v4.x + tanhf_(f.y + qa.y) * v4.y
                 + tanhf_(f.z + qa.z) * v4.z + tanhf_(f.w + qa.w) * v4.w;
        float sc = tanhf_(f.x + qc.x) * v4.x + tanhf_(f.y + qc.y) * v4.y
                 + tanhf_(f.z + qc.z) * v4.z + tanhf_(f.w + qc.w) * v4.w;
        for (int off = 32; off; off >>= 1) {
            sa += __shfl_down(sa, off);
            sc += __shfl_down(sc, off);
        }
        if ((t & 63) == 0) { lds[t >> 6] = sa; lds[4 + (t >> 6)] = sc; }
        __syncthreads();
        if (t == 0) {
            float ng = ws[OFF_NEG + i];
            lds[8] = lds[0] + lds[1] + lds[2] + lds[3] + ng;
            lds[9] = lds[4] + lds[5] + lds[6] + lds[7] + ng;
        }
        __syncthreads();
        float Sa = lds[8], Sc = lds[9];
        __syncthreads();
        // online softmax update, actor
        float mna = fmaxf(ma, Sa);
        float sca = __expf(ma - mna), ea = __expf(Sa - mna);
        la = la * sca + ea;
        ca.x = ca.x * sca + ea * f.x; ca.y = ca.y * sca + ea * f.y;
        ca.z = ca.z * sca + ea * f.z; ca.w = ca.w * sca + ea * f.w;
        ma = mna;
        // critic
        float mnc = fmaxf(mc, Sc);
        float scc = __expf(mc - mnc), ec = __expf(Sc - mnc);
        lc = lc * scc + ec;
        cc.x = cc.x * scc + ec * f.x; cc.y = cc.y * scc + ec * f.y;
        cc.z = cc.z * scc + ec * f.z; cc.w = cc.w * scc + ec * f.w;
        mc = mnc;
    }
    float* gp = ws + OFF_GPART + (b * 2 + 0) * 1028;
    if (t == 0) { gp[0] = ma; gp[1] = la; }
    *(float4*)&gp[4 + t * 4] = ca;
    gp = ws + OFF_GPART + (b * 2 + 1) * 1028;
    if (t == 0) { gp[0] = mc; gp[1] = lc; }
    *(float4*)&gp[4 + t * 4] = cc;
}

// ---------------- combine glimpse partials -> q; write states output for actor ----------------
// grid 8, block 256
__global__ __launch_bounds__(256) void k_combine(float* __restrict__ ws,
                                                 float* __restrict__ out, int step) {
    const int tid = blockIdx.x * 256 + threadIdx.x;  // 0..2047
    const int cid = tid >> 10, k = tid & 1023;
    const float* gp = ws + OFF_GPART + cid * 1028;
    float m = -1e30f;
    for (int b = 0; b < NB_PASS; b++) m = fmaxf(m, gp[b * 2056]);
    float l = 0.0f, cx = 0.0f;
    for (int b = 0; b < NB_PASS; b++) {
        float w = __expf(gp[b * 2056] - m);
        l  += gp[b * 2056 + 1] * w;
        cx += gp[b * 2056 + 4 + k] * w;
    }
    float q = cx / l;
    ws[OFF_Q + cid * 1024 + k] = q;
    if (cid == 0) out[8 + step * 1024 + k] = q;
}

// ---------------- qw2 = q @ attn_wq ----------------
// grid (4, 8, 2), block 256
__global__ __launch_bounds__(256) void k_q2(const float* __restrict__ attn_wq,
                                            float* __restrict__ ws) {
    const int kb = blockIdx.x, jc = blockIdx.y, cid = blockIdx.z;
    const int t = threadIdx.x;
    __shared__ float qloc[128];
    if (t < 128) qloc[t] = ws[OFF_Q + cid * 1024 + jc * 128 + t];
    __syncthreads();
    const int k = kb * 256 + t;
    float acc = 0.0f;
#pragma unroll 8
    for (int jj = 0; jj < 128; jj++) acc += qloc[jj] * attn_wq[(jc * 128 + jj) * 1024 + k];
    atomicAdd(&ws[OFF_QW2 + cid * 1024 + k], acc);
}

// ---------------- attention pass over attn_feat: actor argmax + critic online ctx over enc ----------------
// grid NB_PASS, block 256
__global__ __launch_bounds__(256) void k_attn(const float* __restrict__ attn_v,
                                              const float* __restrict__ enc,
                                              float* __restrict__ ws,
                                              float* __restrict__ out, int step) {
    const int t = threadIdx.x, b = blockIdx.x;
    float4 qa = *(const float4*)&ws[OFF_QW2 + t * 4];
    float4 qc = *(const float4*)&ws[OFF_QW2 + 1024 + t * 4];
    float4 v4 = *(const float4*)&attn_v[t * 4];
    const float* af = ws + OFF_ATTN;
    float bm = -1e30f;
    int bi = 0;
    float mc = -1e30f, lc = 0.0f;
    float4 cc = make_float4(0, 0, 0, 0);
    __shared__ float lds[32];
    for (int i = b; i < NN; i += NB_PASS) {
        float4 f = *(const float4*)&af[i * 1024 + t * 4];
        float4 e = *(const float4*)&enc[i * 1024 + t * 4];
        float sa = tanhf_(f.x + qa.x) * v4.x + tanhf_(f.y + qa.y) * v4.y
                 + tanhf_(f.z + qa.z) * v4.z + tanhf_(f.w + qa.w) * v4.w;
        float sc = tanhf_(f.x + qc.x) * v4.x + tanhf_(f.y + qc.y) * v4.y
                 + tanhf_(f.z + qc.z) * v4.z + tanhf_(f.w + qc.w) * v4.w;
        for (int off = 32; off; off >>= 1) {
            sa += __shfl_down(sa, off);
            sc += __shfl_down(sc, off);
        }
        if ((t & 63) == 0) { lds[t >> 6] = sa; lds[4 + (t >> 6)] = sc; }
        __syncthreads();
        if (t == 0) {
            float ng = ws[OFF_NEG + i];
            lds[8] = lds[0] + lds[1] + lds[2] + lds[3] + ng + ws[OFF_SEL + i];
            lds[9] = lds[4] + lds[5] + lds[6] + lds[7] + ng;
        }
        __syncthreads();
        float Sa = lds[8], Sc = lds[9];
        __syncthreads();
        if (Sa > bm) { bm = Sa; bi = i; }  // strictly greater -> keeps first max (i increasing)
        float mnc = fmaxf(mc, Sc);
        float scc = __expf(mc - mnc), ec = __expf(Sc - mnc);
        lc = lc * scc + ec;
        cc.x = cc.x * scc + ec * e.x; cc.y = cc.y * scc + ec * e.y;
        cc.z = cc.z * scc + ec * e.z; cc.w = cc.w * scc + ec * e.w;
        mc = mnc;
    }
    if (t == 0) {
        ws[OFF_AMAXV + b] = bm;
        ((int*)(ws + OFF_AMAXI))[b] = bi;
    }
    float* cp = ws + OFF_CPART + b * 1028;
    if (t == 0) { cp[0] = mc; cp[1] = lc; }
    *(float4*)&cp[4 + t * 4] = cc;
    if (b == 0 && t == 0) out[8 + NSTEP * 1024 + step] = 0.0f;  // zero scores[step]
}

// ---------------- finalize: argmax, sel update, next actor x; critic ctx + score ----------------
// grid 8, block 128
__global__ __launch_bounds__(128) void k_final(const float* __restrict__ enc,
                                               const float* __restrict__ score_w,
                                               const float* __restrict__ score_b,
                                               float* __restrict__ ws,
                                               float* __restrict__ out, int step) {
    const int t = threadIdx.x, b = blockIdx.x;
    __shared__ float sv[128];
    __shared__ int si[128];
    sv[t] = ws[OFF_AMAXV + t];
    si[t] = ((const int*)(ws + OFF_AMAXI))[t];
    __syncthreads();
    for (int off = 64; off; off >>= 1) {
        if (t < off) {
            float v2 = sv[t + off];
            int i2 = si[t + off];
            if (v2 > sv[t] || (v2 == sv[t] && i2 < si[t])) { sv[t] = v2; si[t] = i2; }
        }
        __syncthreads();
    }
    const int besti = si[0];
    const int k = b * 128 + t;
    ws[OFF_X + k] = enc[besti * 1024 + k];  // next actor LSTM input
    // critic: combine online-softmax partials over enc_out
    const float* cp = ws + OFF_CPART;
    float m = -1e30f;
    for (int bb = 0; bb < NB_PASS; bb++) m = fmaxf(m, cp[bb * 1028]);
    float l = 0.0f, cx = 0.0f;
    for (int bb = 0; bb < NB_PASS; bb++) {
        float w = __expf(cp[bb * 1028] - m);
        l  += cp[bb * 1028 + 1] * w;
        cx += cp[bb * 1028 + 4 + k] * w;
    }
    float ctx = cx / l;
    ws[OFF_X + 1024 + k] = ctx;  // next critic LSTM input
    float p = ctx * score_w[k];
    for (int off = 32; off; off >>= 1) p += __shfl_down(p, off);
    __shared__ float ps[2];
    if ((t & 63) == 0) ps[t >> 6] = p;
    __syncthreads();
    if (t == 0) atomicAdd(&out[8 + NSTEP * 1024 + step], ps[0] + ps[1]);
    if (b == 0 && t == 0) {
        out[step] = (float)besti;
        ws[OFF_SEL + besti] = -1e18f;
        atomicAdd(&out[8 + NSTEP * 1024 + step], score_b[0]);
    }
}

extern "C" void kernel_launch(void* const* d_in, const int* in_sizes, int n_in,
                              void* d_out, int out_size, void* d_ws, size_t ws_size,
                              hipStream_t stream) {
    const float* enc     = (const float*)d_in[0];
    const int*   mask    = (const int*)d_in[1];
    const float* attn_wm = (const float*)d_in[2];
    const float* attn_wq = (const float*)d_in[3];
    const float* attn_v  = (const float*)d_in[4];
    const float* hop_wm  = (const float*)d_in[5];
    const float* hop_wq  = (const float*)d_in[6];
    const float* hop_v   = (const float*)d_in[7];
    const float* init_i  = (const float*)d_in[8];
    const float* init_h  = (const float*)d_in[9];
    const float* init_c  = (const float*)d_in[10];
    const float* w_ih    = (const float*)d_in[11];
    const float* w_hh    = (const float*)d_in[12];
    const float* b_ih    = (const float*)d_in[13];
    const float* b_hh    = (const float*)d_in[14];
    const float* score_w = (const float*)d_in[15];
    const float* score_b = (const float*)d_in[16];
    float* ws  = (float*)d_ws;
    float* out = (float*)d_out;

    k_init<<<32, 256, 0, stream>>>(mask, init_h, init_c, init_i, ws);
    k_gemm<<<dim3(16, 128, 2), 256, 0, stream>>>(enc, attn_wm, hop_wm, ws);

    for (int t = 0; t < NSTEP; t++) {
        const int par = t & 1;
        k_lstm<<<512, 256, 0, stream>>>(w_ih, w_hh, b_ih, b_hh, ws, par);
        k_hq<<<dim3(4, 8, 2), 256, 0, stream>>>(hop_wq, ws, par);
        k_glimpse<<<NB_PASS, 256, 0, stream>>>(hop_v, ws);
        k_combine<<<8, 256, 0, stream>>>(ws, out, t);
        k_q2<<<dim3(4, 8, 2), 256, 0, stream>>>(attn_wq, ws);
        k_attn<<<NB_PASS, 256, 0, stream>>>(attn_v, enc, ws, out, t);
        k_final<<<8, 128, 0, stream>>>(enc, score_w, score_b, ws, out, t);
    }
}

// Round 2
// 2286.768 us; speedup vs baseline: 1.2382x; 1.2382x over previous
//
#include <hip/hip_runtime.h>
#include <hip/hip_bf16.h>

// Problem constants (hardcoded per reference: N=8192, D=H=1024, NSTEP=8)
#define NN 8192
#define HH 1024
#define NSTEP 8

// ---- workspace layout (float offsets) ----
#define OFF_ATTN   0                     // attn_feat [8192*1024]
#define OFF_HOP    8388608               // hop_feat  [8192*1024]
#define BASE2      16777216
#define OFF_NEG    (BASE2 + 0)           // [8192]
#define OFF_SEL    (BASE2 + 8192)        // [8192]
#define OFF_H      (BASE2 + 16384)       // h[parity][chain][1024]
#define OFF_C      (BASE2 + 20480)       // c[parity][chain][1024]
#define OFF_X      (BASE2 + 24576)       // x[chain][1024]
#define OFF_G      (BASE2 + 26624)       // g[chain][4096]
#define OFF_QW     (BASE2 + 34816)       // qw[chain][1024]   (h @ hop_wq)
#define OFF_QW2    (BASE2 + 36864)       // qw2[chain][1024]  (q @ attn_wq)
#define OFF_Q      (BASE2 + 38912)       // q[chain][1024]    (glimpse output)
#define OFF_GPART  (BASE2 + 40960)       // glimpse partials [256][2][1028] {m,l,pad,pad,ctx[1024]}
#define OFF_CPART  (BASE2 + 567296)      // critic attn partials [256][1028]
#define OFF_AMAXV  (BASE2 + 830464)      // [256] block max score
#define OFF_AMAXI  (BASE2 + 830720)      // [256] block argmax (int bits)

#define NB_PASS 256                      // blocks for N-pass kernels (512 thr each)

__device__ __forceinline__ float sigmoidf_(float x) {
    return 1.0f / (1.0f + __expf(-x));
}
__device__ __forceinline__ float tanhf_(float x) {
    float e = __expf(2.0f * x);
    return 1.0f - 2.0f / (e + 1.0f);
}

// score partial over a lane's 16-column chunk
__device__ __forceinline__ float score16(const float4* f, const float4* q, const float4* v) {
    float s = 0.0f;
#pragma unroll
    for (int j = 0; j < 4; j++) {
        s += tanhf_(f[j].x + q[j].x) * v[j].x;
        s += tanhf_(f[j].y + q[j].y) * v[j].y;
        s += tanhf_(f[j].z + q[j].z) * v[j].z;
        s += tanhf_(f[j].w + q[j].w) * v[j].w;
    }
    return s;
}

// online-softmax update of (m,l,ctx16) with score S and value chunk f
__device__ __forceinline__ void osm_update(float S, const float4* f, float& m, float& l, float4* c) {
    float mn = fmaxf(m, S);
    float sc = __expf(m - mn), e = __expf(S - mn);
    l = l * sc + e;
#pragma unroll
    for (int j = 0; j < 4; j++) {
        c[j].x = c[j].x * sc + e * f[j].x;
        c[j].y = c[j].y * sc + e * f[j].y;
        c[j].z = c[j].z * sc + e * f[j].z;
        c[j].w = c[j].w * sc + e * f[j].w;
    }
    m = mn;
}

// ---------------- init ----------------
__global__ __launch_bounds__(256) void k_init(const int* __restrict__ mask,
                                              const float* __restrict__ init_h,
                                              const float* __restrict__ init_c,
                                              const float* __restrict__ init_i,
                                              float* __restrict__ ws) {
    int i = blockIdx.x * 256 + threadIdx.x;
    if (i < NN) {
        ws[OFF_NEG + i] = (mask[i] == 0) ? -1e8f : 0.0f;
        ws[OFF_SEL + i] = 0.0f;
    }
    if (i < HH) {
        ws[OFF_H + i]        = init_h[i];
        ws[OFF_H + 1024 + i] = init_h[i];
        ws[OFF_C + i]        = init_c[i];
        ws[OFF_C + 1024 + i] = init_c[i];
        ws[OFF_X + i]        = init_i[i];
        ws[OFF_X + 1024 + i] = init_i[i];
    }
}

// ---------------- GEMM: feats = enc @ {attn_wm, hop_wm}, 128x128 tile, 8x8/thread ----------------
// grid (8, 64, 2), block 256
__global__ __launch_bounds__(256, 4) void k_gemm(const float* __restrict__ A,
                                                 const float* __restrict__ W0,
                                                 const float* __restrict__ W1,
                                                 float* __restrict__ ws) {
    const float* B = blockIdx.z ? W1 : W0;
    float* Cout = ws + (blockIdx.z ? OFF_HOP : OFF_ATTN);
    const int rowbase = blockIdx.y * 128;
    const int colbase = blockIdx.x * 128;
    __shared__ float As[16][132];  // As[k][m] transposed
    __shared__ float Bs[16][132];  // Bs[k][n]
    const int t  = threadIdx.x;
    const int tx = t & 15, ty = t >> 4;
    const int ar = t >> 1, aks = (t & 1) * 8;   // A staging: row, k-half
    const int bk = t >> 4, bc = (t & 15) * 8;   // B staging: k-row, col group
    float acc[8][8] = {};
    for (int kk = 0; kk < 1024; kk += 16) {
        float4 a0 = *(const float4*)&A[(rowbase + ar) * 1024 + kk + aks];
        float4 a1 = *(const float4*)&A[(rowbase + ar) * 1024 + kk + aks + 4];
        float4 b0 = *(const float4*)&B[(kk + bk) * 1024 + colbase + bc];
        float4 b1 = *(const float4*)&B[(kk + bk) * 1024 + colbase + bc + 4];
        __syncthreads();
        As[aks + 0][ar] = a0.x; As[aks + 1][ar] = a0.y;
        As[aks + 2][ar] = a0.z; As[aks + 3][ar] = a0.w;
        As[aks + 4][ar] = a1.x; As[aks + 5][ar] = a1.y;
        As[aks + 6][ar] = a1.z; As[aks + 7][ar] = a1.w;
        *(float4*)&Bs[bk][bc]     = b0;
        *(float4*)&Bs[bk][bc + 4] = b1;
        __syncthreads();
#pragma unroll
        for (int k = 0; k < 16; k++) {
            float4 x0 = *(const float4*)&As[k][ty * 8];
            float4 x1 = *(const float4*)&As[k][ty * 8 + 4];
            float4 y0 = *(const float4*)&Bs[k][tx * 8];
            float4 y1 = *(const float4*)&Bs[k][tx * 8 + 4];
            float xa[8] = {x0.x, x0.y, x0.z, x0.w, x1.x, x1.y, x1.z, x1.w};
            float yb[8] = {y0.x, y0.y, y0.z, y0.w, y1.x, y1.y, y1.z, y1.w};
#pragma unroll
            for (int i = 0; i < 8; i++)
#pragma unroll
                for (int j = 0; j < 8; j++)
                    acc[i][j] += xa[i] * yb[j];
        }
    }
#pragma unroll
    for (int i = 0; i < 8; i++) {
        float4 o0 = make_float4(acc[i][0], acc[i][1], acc[i][2], acc[i][3]);
        float4 o1 = make_float4(acc[i][4], acc[i][5], acc[i][6], acc[i][7]);
        float* cr = &Cout[(size_t)(rowbase + ty * 8 + i) * 1024 + colbase + tx * 8];
        *(float4*)cr       = o0;
        *(float4*)(cr + 4) = o1;
    }
}

// ---------------- LSTM gates for both chains; also zeroes qw/qw2 ----------------
__global__ __launch_bounds__(256) void k_lstm(const float* __restrict__ w_ih,
                                              const float* __restrict__ w_hh,
                                              const float* __restrict__ b_ih,
                                              const float* __restrict__ b_hh,
                                              float* __restrict__ ws, int parity) {
    const int t = threadIdx.x;
    if (blockIdx.x == 0) {
        for (int i = t; i < 4096; i += 256) ws[OFF_QW + i] = 0.0f;  // qw + qw2 contiguous
    }
    float4 xa = ((const float4*)(ws + OFF_X))[t];
    float4 xc = ((const float4*)(ws + OFF_X + 1024))[t];
    float4 ha = ((const float4*)(ws + OFF_H + parity * 2048))[t];
    float4 hc = ((const float4*)(ws + OFF_H + parity * 2048 + 1024))[t];
    __shared__ float lds[16];
    const int j0 = blockIdx.x * 8;
#pragma unroll
    for (int r = 0; r < 8; r++) {
        const int j = j0 + r;
        float4 wi = *(const float4*)&w_ih[j * 1024 + t * 4];
        float4 wh = *(const float4*)&w_hh[j * 1024 + t * 4];
        float pa = wi.x * xa.x + wi.y * xa.y + wi.z * xa.z + wi.w * xa.w
                 + wh.x * ha.x + wh.y * ha.y + wh.z * ha.z + wh.w * ha.w;
        float pc = wi.x * xc.x + wi.y * xc.y + wi.z * xc.z + wi.w * xc.w
                 + wh.x * hc.x + wh.y * hc.y + wh.z * hc.z + wh.w * hc.w;
        for (int off = 32; off; off >>= 1) {
            pa += __shfl_down(pa, off);
            pc += __shfl_down(pc, off);
        }
        if ((t & 63) == 0) { lds[t >> 6] = pa; lds[8 + (t >> 6)] = pc; }
        __syncthreads();
        if (t == 0) {
            float bb = b_ih[j] + b_hh[j];
            ws[OFF_G + j]        = lds[0] + lds[1] + lds[2] + lds[3] + bb;
            ws[OFF_G + 4096 + j] = lds[8] + lds[9] + lds[10] + lds[11] + bb;
        }
        __syncthreads();
    }
}

// ---------------- h,c update (persist to parity^1) + qw = h @ hop_wq ----------------
__global__ __launch_bounds__(256) void k_hq(const float* __restrict__ hop_wq,
                                            float* __restrict__ ws, int parity) {
    const int kb = blockIdx.x, jc = blockIdx.y, cid = blockIdx.z;
    const int t = threadIdx.x;
    __shared__ float hloc[128];
    const float* g    = ws + OFF_G + cid * 4096;
    const float* cold = ws + OFF_C + parity * 2048 + cid * 1024;
    float* hnew = ws + OFF_H + (parity ^ 1) * 2048 + cid * 1024;
    float* cnew = ws + OFF_C + (parity ^ 1) * 2048 + cid * 1024;
    const int j0 = jc * 128;
    if (t < 128) {
        const int j = j0 + t;
        float ig = sigmoidf_(g[j]);
        float fg = sigmoidf_(g[1024 + j]);
        float gg = tanhf_(g[2048 + j]);
        float og = sigmoidf_(g[3072 + j]);
        float cv = fg * cold[j] + ig * gg;
        float hv = og * tanhf_(cv);
        hloc[t] = hv;
        if (kb == 0) { hnew[j] = hv; cnew[j] = cv; }
    }
    __syncthreads();
    const int k = kb * 256 + t;
    float acc = 0.0f;
#pragma unroll 8
    for (int jj = 0; jj < 128; jj++) acc += hloc[jj] * hop_wq[(j0 + jj) * 1024 + k];
    atomicAdd(&ws[OFF_QW + cid * 1024 + k], acc);
}

// ---------------- glimpse: wave-per-row online-softmax over hop_feat (both chains) ----------------
// grid NB_PASS(256), block 512 (8 waves)
__global__ __launch_bounds__(512, 2) void k_glimpse(const float* __restrict__ hop_v,
                                                    float* __restrict__ ws) {
    const int t = threadIdx.x, b = blockIdx.x;
    const int lane = t & 63, w = t >> 6;
    float4 qa[4], qc[4], v4[4];
#pragma unroll
    for (int j = 0; j < 4; j++) {
        qa[j] = *(const float4*)&ws[OFF_QW + lane * 16 + j * 4];
        qc[j] = *(const float4*)&ws[OFF_QW + 1024 + lane * 16 + j * 4];
        v4[j] = *(const float4*)&hop_v[lane * 16 + j * 4];
    }
    const float* hop = ws + OFF_HOP;
    float ma = -1e30f, la = 0.0f, mc = -1e30f, lc = 0.0f;
    float4 ca[4] = {}, cc[4] = {};
    for (int i = b * 8 + w; i < NN; i += 2048) {
        const float* rowp = hop + (size_t)i * 1024 + lane * 16;
        float4 f[4];
#pragma unroll
        for (int j = 0; j < 4; j++) f[j] = *(const float4*)&rowp[j * 4];
        float sa = score16(f, qa, v4);
        float sc = score16(f, qc, v4);
#pragma unroll
        for (int off = 1; off < 64; off <<= 1) {
            sa += __shfl_xor(sa, off);
            sc += __shfl_xor(sc, off);
        }
        float ng = ws[OFF_NEG + i];
        osm_update(sa + ng, f, ma, la, ca);
        osm_update(sc + ng, f, mc, lc, cc);
    }
    // block combine (two passes over shared ctx buffer)
    __shared__ float sm[8], sl[8];
    __shared__ float sctx[8][1024];
    // actor
    if (lane == 0) { sm[w] = ma; sl[w] = la; }
#pragma unroll
    for (int j = 0; j < 4; j++) *(float4*)&sctx[w][lane * 16 + j * 4] = ca[j];
    __syncthreads();
    {
        float m = -1e30f;
#pragma unroll
        for (int ww = 0; ww < 8; ww++) m = fmaxf(m, sm[ww]);
        float l = 0.0f, a0 = 0.0f, a1 = 0.0f;
        const int k = t * 2;
#pragma unroll
        for (int ww = 0; ww < 8; ww++) {
            float wg = __expf(sm[ww] - m);
            l  += sl[ww] * wg;
            a0 += sctx[ww][k] * wg;
            a1 += sctx[ww][k + 1] * wg;
        }
        float* gp = ws + OFF_GPART + (size_t)(b * 2 + 0) * 1028;
        if (t == 0) { gp[0] = m; gp[1] = l; }
        gp[4 + k] = a0; gp[4 + k + 1] = a1;
    }
    __syncthreads();
    // critic
    if (lane == 0) { sm[w] = mc; sl[w] = lc; }
#pragma unroll
    for (int j = 0; j < 4; j++) *(float4*)&sctx[w][lane * 16 + j * 4] = cc[j];
    __syncthreads();
    {
        float m = -1e30f;
#pragma unroll
        for (int ww = 0; ww < 8; ww++) m = fmaxf(m, sm[ww]);
        float l = 0.0f, a0 = 0.0f, a1 = 0.0f;
        const int k = t * 2;
#pragma unroll
        for (int ww = 0; ww < 8; ww++) {
            float wg = __expf(sm[ww] - m);
            l  += sl[ww] * wg;
            a0 += sctx[ww][k] * wg;
            a1 += sctx[ww][k + 1] * wg;
        }
        float* gp = ws + OFF_GPART + (size_t)(b * 2 + 1) * 1028;
        if (t == 0) { gp[0] = m; gp[1] = l; }
        gp[4 + k] = a0; gp[4 + k + 1] = a1;
    }
}

// ---------------- combine glimpse partials -> q; write states output; zero score slot ----------------
// grid 8, block 256
__global__ __launch_bounds__(256) void k_combine(float* __restrict__ ws,
                                                 float* __restrict__ out, int step) {
    const int tid = blockIdx.x * 256 + threadIdx.x;  // 0..2047
    const int cid = tid >> 10, k = tid & 1023;
    if (tid == 0) out[8 + NSTEP * 1024 + step] = 0.0f;
    const float* gp = ws + OFF_GPART + cid * 1028;
    float m = -1e30f;
    for (int b = 0; b < NB_PASS; b++) m = fmaxf(m, gp[(size_t)b * 2056]);
    float l = 0.0f, cx = 0.0f;
    for (int b = 0; b < NB_PASS; b++) {
        float wgt = __expf(gp[(size_t)b * 2056] - m);
        l  += gp[(size_t)b * 2056 + 1] * wgt;
        cx += gp[(size_t)b * 2056 + 4 + k] * wgt;
    }
    float q = cx / l;
    ws[OFF_Q + cid * 1024 + k] = q;
    if (cid == 0) out[8 + step * 1024 + k] = q;
}

// ---------------- qw2 = q @ attn_wq ----------------
__global__ __launch_bounds__(256) void k_q2(const float* __restrict__ attn_wq,
                                            float* __restrict__ ws) {
    const int kb = blockIdx.x, jc = blockIdx.y, cid = blockIdx.z;
    const int t = threadIdx.x;
    __shared__ float qloc[128];
    if (t < 128) qloc[t] = ws[OFF_Q + cid * 1024 + jc * 128 + t];
    __syncthreads();
    const int k = kb * 256 + t;
    float acc = 0.0f;
#pragma unroll 8
    for (int jj = 0; jj < 128; jj++) acc += qloc[jj] * attn_wq[(jc * 128 + jj) * 1024 + k];
    atomicAdd(&ws[OFF_QW2 + cid * 1024 + k], acc);
}

// ---------------- attention: wave-per-row actor argmax + critic online ctx over enc ----------------
// grid NB_PASS(256), block 512 (8 waves)
__global__ __launch_bounds__(512, 2) void k_attn(const float* __restrict__ attn_v,
                                                 const float* __restrict__ enc,
                                                 float* __restrict__ ws) {
    const int t = threadIdx.x, b = blockIdx.x;
    const int lane = t & 63, w = t >> 6;
    float4 qa[4], qc[4], v4[4];
#pragma unroll
    for (int j = 0; j < 4; j++) {
        qa[j] = *(const float4*)&ws[OFF_QW2 + lane * 16 + j * 4];
        qc[j] = *(const float4*)&ws[OFF_QW2 + 1024 + lane * 16 + j * 4];
        v4[j] = *(const float4*)&attn_v[lane * 16 + j * 4];
    }
    const float* af = ws + OFF_ATTN;
    float bm = -1e30f;
    int bi = 0;
    float mc = -1e30f, lc = 0.0f;
    float4 cc[4] = {};
    for (int i = b * 8 + w; i < NN; i += 2048) {
        const float* rowp = af + (size_t)i * 1024 + lane * 16;
        const float* erow = enc + (size_t)i * 1024 + lane * 16;
        float4 f[4], e[4];
#pragma unroll
        for (int j = 0; j < 4; j++) { f[j] = *(const float4*)&rowp[j * 4]; e[j] = *(const float4*)&erow[j * 4]; }
        float sa = score16(f, qa, v4);
        float sc = score16(f, qc, v4);
#pragma unroll
        for (int off = 1; off < 64; off <<= 1) {
            sa += __shfl_xor(sa, off);
            sc += __shfl_xor(sc, off);
        }
        float ng = ws[OFF_NEG + i];
        float Sa = sa + ng + ws[OFF_SEL + i];
        if (Sa > bm) { bm = Sa; bi = i; }  // strict > : keeps first max within wave (i increasing)
        osm_update(sc + ng, e, mc, lc, cc);
    }
    __shared__ float swv[8];
    __shared__ int swi[8];
    __shared__ float sm[8], sl[8];
    __shared__ float sctx[8][1024];
    if (lane == 0) { swv[w] = bm; swi[w] = bi; sm[w] = mc; sl[w] = lc; }
#pragma unroll
    for (int j = 0; j < 4; j++) *(float4*)&sctx[w][lane * 16 + j * 4] = cc[j];
    __syncthreads();
    if (t == 0) {
        float v = swv[0]; int ii = swi[0];
        for (int ww = 1; ww < 8; ww++) {
            if (swv[ww] > v || (swv[ww] == v && swi[ww] < ii)) { v = swv[ww]; ii = swi[ww]; }
        }
        ws[OFF_AMAXV + b] = v;
        ((int*)(ws + OFF_AMAXI))[b] = ii;
    }
    {
        float m = -1e30f;
#pragma unroll
        for (int ww = 0; ww < 8; ww++) m = fmaxf(m, sm[ww]);
        float l = 0.0f, a0 = 0.0f, a1 = 0.0f;
        const int k = t * 2;
#pragma unroll
        for (int ww = 0; ww < 8; ww++) {
            float wg = __expf(sm[ww] - m);
            l  += sl[ww] * wg;
            a0 += sctx[ww][k] * wg;
            a1 += sctx[ww][k + 1] * wg;
        }
        float* cp = ws + OFF_CPART + (size_t)b * 1028;
        if (t == 0) { cp[0] = m; cp[1] = l; }
        cp[4 + k] = a0; cp[4 + k + 1] = a1;
    }
}

// ---------------- finalize: argmax, sel update, next actor x; critic ctx + score ----------------
// grid 8, block 128
__global__ __launch_bounds__(128) void k_final(const float* __restrict__ enc,
                                               const float* __restrict__ score_w,
                                               const float* __restrict__ score_b,
                                               float* __restrict__ ws,
                                               float* __restrict__ out, int step) {
    const int t = threadIdx.x, b = blockIdx.x;
    __shared__ float sv[128];
    __shared__ int si[128];
    {
        float v1 = ws[OFF_AMAXV + t];
        int   i1 = ((const int*)(ws + OFF_AMAXI))[t];
        float v2 = ws[OFF_AMAXV + 128 + t];
        int   i2 = ((const int*)(ws + OFF_AMAXI))[128 + t];
        if (v2 > v1 || (v2 == v1 && i2 < i1)) { v1 = v2; i1 = i2; }
        sv[t] = v1; si[t] = i1;
    }
    __syncthreads();
    for (int off = 64; off; off >>= 1) {
        if (t < off) {
            float v2 = sv[t + off];
            int i2 = si[t + off];
            if (v2 > sv[t] || (v2 == sv[t] && i2 < si[t])) { sv[t] = v2; si[t] = i2; }
        }
        __syncthreads();
    }
    const int besti = si[0];
    const int k = b * 128 + t;
    ws[OFF_X + k] = enc[(size_t)besti * 1024 + k];  // next actor LSTM input
    const float* cp = ws + OFF_CPART;
    float m = -1e30f;
    for (int bb = 0; bb < NB_PASS; bb++) m = fmaxf(m, cp[(size_t)bb * 1028]);
    float l = 0.0f, cx = 0.0f;
    for (int bb = 0; bb < NB_PASS; bb++) {
        float wgt = __expf(cp[(size_t)bb * 1028] - m);
        l  += cp[(size_t)bb * 1028 + 1] * wgt;
        cx += cp[(size_t)bb * 1028 + 4 + k] * wgt;
    }
    float ctx = cx / l;
    ws[OFF_X + 1024 + k] = ctx;  // next critic LSTM input
    float p = ctx * score_w[k];
    for (int off = 32; off; off >>= 1) p += __shfl_down(p, off);
    __shared__ float ps[2];
    if ((t & 63) == 0) ps[t >> 6] = p;
    __syncthreads();
    if (t == 0) atomicAdd(&out[8 + NSTEP * 1024 + step], ps[0] + ps[1]);
    if (b == 0 && t == 0) {
        out[step] = (float)besti;
        ws[OFF_SEL + besti] = -1e18f;
        atomicAdd(&out[8 + NSTEP * 1024 + step], score_b[0]);
    }
}

extern "C" void kernel_launch(void* const* d_in, const int* in_sizes, int n_in,
                              void* d_out, int out_size, void* d_ws, size_t ws_size,
                              hipStream_t stream) {
    const float* enc     = (const float*)d_in[0];
    const int*   mask    = (const int*)d_in[1];
    const float* attn_wm = (const float*)d_in[2];
    const float* attn_wq = (const float*)d_in[3];
    const float* attn_v  = (const float*)d_in[4];
    const float* hop_wm  = (const float*)d_in[5];
    const float* hop_wq  = (const float*)d_in[6];
    const float* hop_v   = (const float*)d_in[7];
    const float* init_i  = (const float*)d_in[8];
    const float* init_h  = (const float*)d_in[9];
    const float* init_c  = (const float*)d_in[10];
    const float* w_ih    = (const float*)d_in[11];
    const float* w_hh    = (const float*)d_in[12];
    const float* b_ih    = (const float*)d_in[13];
    const float* b_hh    = (const float*)d_in[14];
    const float* score_w = (const float*)d_in[15];
    const float* score_b = (const float*)d_in[16];
    float* ws  = (float*)d_ws;
    float* out = (float*)d_out;

    k_init<<<32, 256, 0, stream>>>(mask, init_h, init_c, init_i, ws);
    k_gemm<<<dim3(8, 64, 2), 256, 0, stream>>>(enc, attn_wm, hop_wm, ws);

    for (int t = 0; t < NSTEP; t++) {
        const int par = t & 1;
        k_lstm<<<512, 256, 0, stream>>>(w_ih, w_hh, b_ih, b_hh, ws, par);
        k_hq<<<dim3(4, 8, 2), 256, 0, stream>>>(hop_wq, ws, par);
        k_glimpse<<<NB_PASS, 512, 0, stream>>>(hop_v, ws);
        k_combine<<<8, 256, 0, stream>>>(ws, out, t);
        k_q2<<<dim3(4, 8, 2), 256, 0, stream>>>(attn_wq, ws);
        k_attn<<<NB_PASS, 512, 0, stream>>>(attn_v, enc, ws);
        k_final<<<8, 128, 0, stream>>>(enc, score_w, score_b, ws, out, t);
    }
}

// Round 4
// 2154.543 us; speedup vs baseline: 1.3142x; 1.0614x over previous
//
#include <hip/hip_runtime.h>
#include <hip/hip_bf16.h>

// Problem constants (reference: N=8192, D=H=1024, NSTEP=8)
#define NN 8192
#define HH 1024
#define NSTEP 8
#define NBLK 256
#define NTHR 512

// ---- workspace layout (float offsets) ----
#define OFF_ATTN   0                     // attn_feat [8192*1024]
#define OFF_HOP    8388608               // hop_feat  [8192*1024]
#define B2         16777216
#define OFF_NEG    (B2 + 0)              // [8192]
#define OFF_SEL    (B2 + 8192)           // [8192]
#define OFF_H      (B2 + 16384)          // h[parity][chain][1024]
#define OFF_C      (B2 + 20480)          // c[parity][chain][1024]
#define OFF_QW     (B2 + 24576)          // qw[chain][1024]
#define OFF_QW2    (B2 + 26624)          // qw2[chain][1024]
#define OFF_GCTXA  (B2 + 28672)          // glimpse ctx actor  [1024] (atomic accum)
#define OFF_GCTXC  (B2 + 29696)          // glimpse ctx critic [1024]
#define OFF_ACTX   (B2 + 30720)          // critic attn ctx    [1024]
#define OFF_GLA    (B2 + 31744)          // glimpse l actor (scalar)
#define OFF_GLC    (B2 + 31745)          // glimpse l critic
#define OFF_AL     (B2 + 31746)          // critic attn l
#define OFF_AMAX   (B2 + 31748)          // packed u64 argmax (8B aligned)
#define OFF_BAR    (B2 + 31752)          // barrier counter (uint)

__device__ __forceinline__ float sigmoidf_(float x) {
    return 1.0f / (1.0f + __expf(-x));
}
__device__ __forceinline__ float tanhf_(float x) {
    float e = __expf(2.0f * x);
    return 1.0f - 2.0f / (e + 1.0f);
}

__device__ __forceinline__ float score16(const float4* f, const float4* q, const float4* v) {
    float s = 0.0f;
#pragma unroll
    for (int j = 0; j < 4; j++) {
        s += tanhf_(f[j].x + q[j].x) * v[j].x;
        s += tanhf_(f[j].y + q[j].y) * v[j].y;
        s += tanhf_(f[j].z + q[j].z) * v[j].z;
        s += tanhf_(f[j].w + q[j].w) * v[j].w;
    }
    return s;
}

// software grid barrier: monotonic counter, device-scope acq-rel
__device__ __forceinline__ void gsync(unsigned int* bar, unsigned int target) {
    __syncthreads();
    if (threadIdx.x == 0) {
        __hip_atomic_fetch_add(bar, 1u, __ATOMIC_ACQ_REL, __HIP_MEMORY_SCOPE_AGENT);
        while (__hip_atomic_load(bar, __ATOMIC_ACQUIRE, __HIP_MEMORY_SCOPE_AGENT) < target)
            __builtin_amdgcn_s_sleep(1);
    }
    __syncthreads();
}

// monotone orderable key for fp32 + first-index tie-break
__device__ __forceinline__ unsigned long long packscore(float f, int i) {
    unsigned int u = __float_as_uint(f);
    unsigned int key = (u & 0x80000000u) ? ~u : (u | 0x80000000u);
    return ((unsigned long long)key << 32) | (unsigned int)(0x7FFFFFFF - i);
}

// ---------------- GEMM: feats = enc @ {attn_wm, hop_wm}, 128x128 tile, 8x8/thread ----------------
// split microtile {c*4, c*4+64}: LDS reads are 2-way conflicted only (free per m136)
__global__ __launch_bounds__(256, 4) void k_gemm(const float* __restrict__ A,
                                                 const float* __restrict__ W0,
                                                 const float* __restrict__ W1,
                                                 float* __restrict__ ws) {
    const float* B = blockIdx.z ? W1 : W0;
    float* Cout = ws + (blockIdx.z ? OFF_HOP : OFF_ATTN);
    const int rowbase = blockIdx.y * 128;
    const int colbase = blockIdx.x * 128;
    __shared__ float As[16][132];
    __shared__ float Bs[16][132];
    const int t  = threadIdx.x;
    const int tx = t & 15;
    const int ty2 = t >> 4;  // 0..15
    const int ar = t >> 1, aks = (t & 1) * 8;
    const int bk = t >> 4, bc = (t & 15) * 8;
    float acc[8][8] = {};
    for (int kk = 0; kk < 1024; kk += 16) {
        float4 a0 = *(const float4*)&A[(size_t)(rowbase + ar) * 1024 + kk + aks];
        float4 a1 = *(const float4*)&A[(size_t)(rowbase + ar) * 1024 + kk + aks + 4];
        float4 b0 = *(const float4*)&B[(size_t)(kk + bk) * 1024 + colbase + bc];
        float4 b1 = *(const float4*)&B[(size_t)(kk + bk) * 1024 + colbase + bc + 4];
        __syncthreads();
        As[aks + 0][ar] = a0.x; As[aks + 1][ar] = a0.y;
        As[aks + 2][ar] = a0.z; As[aks + 3][ar] = a0.w;
        As[aks + 4][ar] = a1.x; As[aks + 5][ar] = a1.y;
        As[aks + 6][ar] = a1.z; As[aks + 7][ar] = a1.w;
        *(float4*)&Bs[bk][bc]     = b0;
        *(float4*)&Bs[bk][bc + 4] = b1;
        __syncthreads();
#pragma unroll
        for (int k = 0; k < 16; k++) {
            float4 x0 = *(const float4*)&As[k][ty2 * 4];
            float4 x1 = *(const float4*)&As[k][ty2 * 4 + 64];
            float4 y0 = *(const float4*)&Bs[k][tx * 4];
            float4 y1 = *(const float4*)&Bs[k][tx * 4 + 64];
            float xa[8] = {x0.x, x0.y, x0.z, x0.w, x1.x, x1.y, x1.z, x1.w};
            float yb[8] = {y0.x, y0.y, y0.z, y0.w, y1.x, y1.y, y1.z, y1.w};
#pragma unroll
            for (int i = 0; i < 8; i++)
#pragma unroll
                for (int j = 0; j < 8; j++)
                    acc[i][j] += xa[i] * yb[j];
        }
    }
#pragma unroll
    for (int i = 0; i < 8; i++) {
        int row = rowbase + ((i < 4) ? (ty2 * 4 + i) : (64 + ty2 * 4 + (i - 4)));
        float* cr = &Cout[(size_t)row * 1024 + colbase];
        *(float4*)&cr[tx * 4]      = make_float4(acc[i][0], acc[i][1], acc[i][2], acc[i][3]);
        *(float4*)&cr[64 + tx * 4] = make_float4(acc[i][4], acc[i][5], acc[i][6], acc[i][7]);
    }
}

// ---------------- persistent fused 8-step decode ----------------
// grid 256 x block 512, 1 block/CU; lane chunk mapping: cols {lane*4 + p*256}
__global__ __launch_bounds__(512) void k_steps(
        const float* __restrict__ enc, const int* __restrict__ mask,
        const float* __restrict__ attn_wq, const float* __restrict__ attn_v,
        const float* __restrict__ hop_wq, const float* __restrict__ hop_v,
        const float* __restrict__ init_h, const float* __restrict__ init_c,
        const float* __restrict__ init_i,
        const float* __restrict__ w_ih, const float* __restrict__ w_hh,
        const float* __restrict__ b_ih, const float* __restrict__ b_hh,
        const float* __restrict__ score_w, const float* __restrict__ score_b,
        float* __restrict__ ws, float* __restrict__ out) {
    const int b = blockIdx.x;
    const int t = threadIdx.x;
    const int w = t >> 6, lane = t & 63;
    __shared__ __align__(16) float smem[8224];
    unsigned int* bar = (unsigned int*)(ws + OFF_BAR);
    unsigned int bt = 0;

    // ---- phase 0: init ----
    {
        int i = b * NTHR + t;
        if (i < NN) {
            ws[OFF_NEG + i] = (mask[i] == 0) ? -1e8f : 0.0f;
            ws[OFF_SEL + i] = 0.0f;
        }
        if (i < 2048) {  // parity-0 h,c for both chains
            ws[OFF_H + i] = init_h[i & 1023];
            ws[OFF_C + i] = init_c[i & 1023];
        }
        if (b == 16) {  // zero atomic accumulators
            for (int c = t; c < 1024; c += NTHR) {
                ws[OFF_GCTXA + c] = 0.0f;
                ws[OFF_GCTXC + c] = 0.0f;
                ws[OFF_ACTX + c]  = 0.0f;
            }
            if (t == 0) {
                ws[OFF_GLA] = 0.0f; ws[OFF_GLC] = 0.0f; ws[OFF_AL] = 0.0f;
                *(unsigned long long*)&ws[OFF_AMAX] = 0ull;
            }
        }
    }
    bt += NBLK; gsync(bar, bt);

    for (int step = 0; step < NSTEP; step++) {
        const int par = step & 1;
        // ===== P1: finalize prev step (block 0) + LSTM both chains =====
        {
            int besti = 0;
            float rinv = 0.0f;
            if (step > 0) {
                unsigned long long pk = *(const unsigned long long*)&ws[OFF_AMAX];
                besti = 0x7FFFFFFF - (int)(unsigned int)(pk & 0xFFFFFFFFull);
                rinv = 1.0f / ws[OFF_AL];
            }
            if (step > 0 && b == 0) {
                float p = ws[OFF_ACTX + t] * rinv * score_w[t]
                        + ws[OFF_ACTX + t + 512] * rinv * score_w[t + 512];
#pragma unroll
                for (int off = 32; off; off >>= 1) p += __shfl_down(p, off);
                if (lane == 0) smem[8192 + w] = p;
                __syncthreads();
                if (t == 0) {
                    float s = 0.0f;
#pragma unroll
                    for (int ww = 0; ww < 8; ww++) s += smem[8192 + ww];
                    out[8 + NSTEP * 1024 + (step - 1)] = s + score_b[0];
                    out[step - 1] = (float)besti;
                    ws[OFF_SEL + besti] = -1e18f;
                }
                __syncthreads();
            }
            const int gw = b * 8 + w;
            if (gw < 1024) {
                const int j = gw;
                float4 xa[4], xc[4], ha[4], hc[4];
#pragma unroll
                for (int p = 0; p < 4; p++) {
                    int kk = lane * 4 + p * 256;
                    if (step == 0) {
                        xa[p] = *(const float4*)&init_i[kk];
                        xc[p] = xa[p];
                    } else {
                        xa[p] = *(const float4*)&enc[(size_t)besti * 1024 + kk];
                        float4 cx = *(const float4*)&ws[OFF_ACTX + kk];
                        xc[p] = make_float4(cx.x * rinv, cx.y * rinv, cx.z * rinv, cx.w * rinv);
                    }
                    ha[p] = *(const float4*)&ws[OFF_H + par * 2048 + kk];
                    hc[p] = *(const float4*)&ws[OFF_H + par * 2048 + 1024 + kk];
                }
                float pa[4], pc[4];
#pragma unroll
                for (int g = 0; g < 4; g++) {
                    const float* wi = w_ih + (size_t)(g * 1024 + j) * 1024;
                    const float* wh = w_hh + (size_t)(g * 1024 + j) * 1024;
                    float sa = 0.0f, sc = 0.0f;
#pragma unroll
                    for (int p = 0; p < 4; p++) {
                        int kk = lane * 4 + p * 256;
                        float4 a = *(const float4*)&wi[kk];
                        float4 hh = *(const float4*)&wh[kk];
                        sa += a.x * xa[p].x + a.y * xa[p].y + a.z * xa[p].z + a.w * xa[p].w
                            + hh.x * ha[p].x + hh.y * ha[p].y + hh.z * ha[p].z + hh.w * ha[p].w;
                        sc += a.x * xc[p].x + a.y * xc[p].y + a.z * xc[p].z + a.w * xc[p].w
                            + hh.x * hc[p].x + hh.y * hc[p].y + hh.z * hc[p].z + hh.w * hc[p].w;
                    }
                    pa[g] = sa; pc[g] = sc;
                }
#pragma unroll
                for (int off = 1; off < 64; off <<= 1) {
#pragma unroll
                    for (int g = 0; g < 4; g++) {
                        pa[g] += __shfl_xor(pa[g], off);
                        pc[g] += __shfl_xor(pc[g], off);
                    }
                }
                if (lane == 0) {
                    float bb0 = b_ih[j] + b_hh[j];
                    float bb1 = b_ih[1024 + j] + b_hh[1024 + j];
                    float bb2 = b_ih[2048 + j] + b_hh[2048 + j];
                    float bb3 = b_ih[3072 + j] + b_hh[3072 + j];
                    {
                        float ig = sigmoidf_(pa[0] + bb0), fg = sigmoidf_(pa[1] + bb1);
                        float gg = tanhf_(pa[2] + bb2),   og = sigmoidf_(pa[3] + bb3);
                        float cv = fg * ws[OFF_C + par * 2048 + j] + ig * gg;
                        ws[OFF_H + (par ^ 1) * 2048 + j] = og * tanhf_(cv);
                        ws[OFF_C + (par ^ 1) * 2048 + j] = cv;
                    }
                    {
                        float ig = sigmoidf_(pc[0] + bb0), fg = sigmoidf_(pc[1] + bb1);
                        float gg = tanhf_(pc[2] + bb2),   og = sigmoidf_(pc[3] + bb3);
                        float cv = fg * ws[OFF_C + par * 2048 + 1024 + j] + ig * gg;
                        ws[OFF_H + (par ^ 1) * 2048 + 1024 + j] = og * tanhf_(cv);
                        ws[OFF_C + (par ^ 1) * 2048 + 1024 + j] = cv;
                    }
                }
            }
        }
        bt += NBLK; gsync(bar, bt);

        // ===== P2: qw = h' @ hop_wq (blocks 0..31); block 32 zeroes attn accums =====
        if (b < 32) {
            const int chain = b >> 4, kb = b & 15;
            const float* hsrc = ws + OFF_H + (par ^ 1) * 2048 + chain * 1024;
            smem[t]       = hsrc[t];
            smem[t + 512] = hsrc[t + 512];
            __syncthreads();
            const int col = kb * 64 + (t & 63);
            const int jg = t >> 6;
            const float* wq = hop_wq + (size_t)jg * 128 * 1024 + col;
            float acc = 0.0f;
#pragma unroll 8
            for (int j = 0; j < 128; j++) acc += smem[jg * 128 + j] * wq[(size_t)j * 1024];
            smem[1024 + t] = acc;
            __syncthreads();
            if (t < 64) {
                float s = 0.0f;
#pragma unroll
                for (int jg2 = 0; jg2 < 8; jg2++) s += smem[1024 + jg2 * 64 + t];
                ws[OFF_QW + chain * 1024 + kb * 64 + t] = s;
            }
        } else if (b == 32) {
            for (int c = t; c < 1024; c += NTHR) ws[OFF_ACTX + c] = 0.0f;
            if (t == 0) {
                ws[OFF_AL] = 0.0f;
                *(unsigned long long*)&ws[OFF_AMAX] = 0ull;
            }
        }
        bt += NBLK; gsync(bar, bt);

        // ===== P3: glimpse pass over hop_feat (both chains), fixed-max softmax =====
        {
            float4 qa[4], qc[4], v4[4];
#pragma unroll
            for (int p = 0; p < 4; p++) {
                int kk = lane * 4 + p * 256;
                qa[p] = *(const float4*)&ws[OFF_QW + kk];
                qc[p] = *(const float4*)&ws[OFF_QW + 1024 + kk];
                v4[p] = *(const float4*)&hop_v[kk];
            }
            float la = 0.0f, lc = 0.0f;
            float4 ca[4] = {}, cc[4] = {};
            for (int i = b * 8 + w; i < NN; i += 2048) {
                const float* row = ws + OFF_HOP + (size_t)i * 1024;
                float4 f[4];
#pragma unroll
                for (int p = 0; p < 4; p++) f[p] = *(const float4*)&row[lane * 4 + p * 256];
                float sa = score16(f, qa, v4);
                float sc = score16(f, qc, v4);
#pragma unroll
                for (int off = 1; off < 64; off <<= 1) {
                    sa += __shfl_xor(sa, off);
                    sc += __shfl_xor(sc, off);
                }
                float ng = ws[OFF_NEG + i];
                float ea = __expf(sa + ng), ec = __expf(sc + ng);
                la += ea; lc += ec;
#pragma unroll
                for (int p = 0; p < 4; p++) {
                    ca[p].x += ea * f[p].x; ca[p].y += ea * f[p].y;
                    ca[p].z += ea * f[p].z; ca[p].w += ea * f[p].w;
                    cc[p].x += ec * f[p].x; cc[p].y += ec * f[p].y;
                    cc[p].z += ec * f[p].z; cc[p].w += ec * f[p].w;
                }
            }
            // block reduce + atomic accumulate: actor
            if (lane == 0) smem[8192 + w] = la;
#pragma unroll
            for (int p = 0; p < 4; p++) *(float4*)&smem[w * 1024 + lane * 4 + p * 256] = ca[p];
            __syncthreads();
            {
                const int k = t * 2;
                float s0 = 0.0f, s1 = 0.0f;
#pragma unroll
                for (int ww = 0; ww < 8; ww++) {
                    s0 += smem[ww * 1024 + k];
                    s1 += smem[ww * 1024 + k + 1];
                }
                atomicAdd(&ws[OFF_GCTXA + k], s0);
                atomicAdd(&ws[OFF_GCTXA + k + 1], s1);
                if (t == 0) {
                    float s = 0.0f;
#pragma unroll
                    for (int ww = 0; ww < 8; ww++) s += smem[8192 + ww];
                    atomicAdd(&ws[OFF_GLA], s);
                }
            }
            __syncthreads();
            // critic
            if (lane == 0) smem[8192 + w] = lc;
#pragma unroll
            for (int p = 0; p < 4; p++) *(float4*)&smem[w * 1024 + lane * 4 + p * 256] = cc[p];
            __syncthreads();
            {
                const int k = t * 2;
                float s0 = 0.0f, s1 = 0.0f;
#pragma unroll
                for (int ww = 0; ww < 8; ww++) {
                    s0 += smem[ww * 1024 + k];
                    s1 += smem[ww * 1024 + k + 1];
                }
                atomicAdd(&ws[OFF_GCTXC + k], s0);
                atomicAdd(&ws[OFF_GCTXC + k + 1], s1);
                if (t == 0) {
                    float s = 0.0f;
#pragma unroll
                    for (int ww = 0; ww < 8; ww++) s += smem[8192 + ww];
                    atomicAdd(&ws[OFF_GLC], s);
                }
            }
            __syncthreads();
        }
        bt += NBLK; gsync(bar, bt);

        // ===== P4: q = ctx/l; qw2 = q @ attn_wq (blocks 0..31); states out (block 0) =====
        if (b < 32) {
            const int chain = b >> 4, kb = b & 15;
            const float linv = 1.0f / ws[chain ? OFF_GLC : OFF_GLA];
            const float* gc = ws + (chain ? OFF_GCTXC : OFF_GCTXA);
            smem[t * 2]     = gc[t * 2] * linv;
            smem[t * 2 + 1] = gc[t * 2 + 1] * linv;
            __syncthreads();
            if (b == 0) {
                out[8 + step * 1024 + t * 2]     = smem[t * 2];
                out[8 + step * 1024 + t * 2 + 1] = smem[t * 2 + 1];
            }
            const int col = kb * 64 + (t & 63);
            const int jg = t >> 6;
            const float* aw = attn_wq + (size_t)jg * 128 * 1024 + col;
            float acc = 0.0f;
#pragma unroll 8
            for (int j = 0; j < 128; j++) acc += smem[jg * 128 + j] * aw[(size_t)j * 1024];
            __syncthreads();
            smem[1024 + t] = acc;
            __syncthreads();
            if (t < 64) {
                float s = 0.0f;
#pragma unroll
                for (int jg2 = 0; jg2 < 8; jg2++) s += smem[1024 + jg2 * 64 + t];
                ws[OFF_QW2 + chain * 1024 + kb * 64 + t] = s;
            }
        }
        bt += NBLK; gsync(bar, bt);

        // ===== P5: attn pass — actor argmax + critic ctx over enc; block 0 zeroes glimpse accums =====
        {
            if (b == 0) {
                for (int c = t; c < 1024; c += NTHR) {
                    ws[OFF_GCTXA + c] = 0.0f;
                    ws[OFF_GCTXC + c] = 0.0f;
                }
                if (t == 0) { ws[OFF_GLA] = 0.0f; ws[OFF_GLC] = 0.0f; }
            }
            float4 qa[4], qc[4], v4[4];
#pragma unroll
            for (int p = 0; p < 4; p++) {
                int kk = lane * 4 + p * 256;
                qa[p] = *(const float4*)&ws[OFF_QW2 + kk];
                qc[p] = *(const float4*)&ws[OFF_QW2 + 1024 + kk];
                v4[p] = *(const float4*)&attn_v[kk];
            }
            float bm = -1e30f;
            int bi = 0;
            float lc = 0.0f;
            float4 cc[4] = {};
            for (int i = b * 8 + w; i < NN; i += 2048) {
                const float* frow = ws + OFF_ATTN + (size_t)i * 1024;
                const float* erow = enc + (size_t)i * 1024;
                float4 f[4], e[4];
#pragma unroll
                for (int p = 0; p < 4; p++) {
                    f[p] = *(const float4*)&frow[lane * 4 + p * 256];
                    e[p] = *(const float4*)&erow[lane * 4 + p * 256];
                }
                float sa = score16(f, qa, v4);
                float sc = score16(f, qc, v4);
#pragma unroll
                for (int off = 1; off < 64; off <<= 1) {
                    sa += __shfl_xor(sa, off);
                    sc += __shfl_xor(sc, off);
                }
                float ng = ws[OFF_NEG + i];
                float Sa = sa + ng + ws[OFF_SEL + i];
                if (Sa > bm) { bm = Sa; bi = i; }
                float ec = __expf(sc + ng);
                lc += ec;
#pragma unroll
                for (int p = 0; p < 4; p++) {
                    cc[p].x += ec * e[p].x; cc[p].y += ec * e[p].y;
                    cc[p].z += ec * e[p].z; cc[p].w += ec * e[p].w;
                }
            }
            unsigned long long* spk = (unsigned long long*)(smem + 8200);
            if (lane == 0) { smem[8192 + w] = lc; spk[w] = packscore(bm, bi); }
#pragma unroll
            for (int p = 0; p < 4; p++) *(float4*)&smem[w * 1024 + lane * 4 + p * 256] = cc[p];
            __syncthreads();
            {
                const int k = t * 2;
                float s0 = 0.0f, s1 = 0.0f;
#pragma unroll
                for (int ww = 0; ww < 8; ww++) {
                    s0 += smem[ww * 1024 + k];
                    s1 += smem[ww * 1024 + k + 1];
                }
                atomicAdd(&ws[OFF_ACTX + k], s0);
                atomicAdd(&ws[OFF_ACTX + k + 1], s1);
                if (t == 0) {
                    float s = 0.0f;
                    unsigned long long mx = 0ull;
#pragma unroll
                    for (int ww = 0; ww < 8; ww++) {
                        s += smem[8192 + ww];
                        if (spk[ww] > mx) mx = spk[ww];
                    }
                    atomicAdd(&ws[OFF_AL], s);
                    atomicMax((unsigned long long*)&ws[OFF_AMAX], mx);
                }
            }
            __syncthreads();
        }
        bt += NBLK; gsync(bar, bt);
    }

    // ===== epilogue: finalize step 7 (block 0) =====
    if (b == 0) {
        unsigned long long pk = *(const unsigned long long*)&ws[OFF_AMAX];
        int besti = 0x7FFFFFFF - (int)(unsigned int)(pk & 0xFFFFFFFFull);
        float rinv = 1.0f / ws[OFF_AL];
        float p = ws[OFF_ACTX + t] * rinv * score_w[t]
                + ws[OFF_ACTX + t + 512] * rinv * score_w[t + 512];
#pragma unroll
        for (int off = 32; off; off >>= 1) p += __shfl_down(p, off);
        if (lane == 0) smem[8192 + w] = p;
        __syncthreads();
        if (t == 0) {
            float s = 0.0f;
#pragma unroll
            for (int ww = 0; ww < 8; ww++) s += smem[8192 + ww];
            out[8 + NSTEP * 1024 + (NSTEP - 1)] = s + score_b[0];
            out[NSTEP - 1] = (float)besti;
        }
    }
}

extern "C" void kernel_launch(void* const* d_in, const int* in_sizes, int n_in,
                              void* d_out, int out_size, void* d_ws, size_t ws_size,
                              hipStream_t stream) {
    const float* enc     = (const float*)d_in[0];
    const int*   mask    = (const int*)d_in[1];
    const float* attn_wm = (const float*)d_in[2];
    const float* attn_wq = (const float*)d_in[3];
    const float* attn_v  = (const float*)d_in[4];
    const float* hop_wm  = (const float*)d_in[5];
    const float* hop_wq  = (const float*)d_in[6];
    const float* hop_v   = (const float*)d_in[7];
    const float* init_i  = (const float*)d_in[8];
    const float* init_h  = (const float*)d_in[9];
    const float* init_c  = (const float*)d_in[10];
    const float* w_ih    = (const float*)d_in[11];
    const float* w_hh    = (const float*)d_in[12];
    const float* b_ih    = (const float*)d_in[13];
    const float* b_hh    = (const float*)d_in[14];
    const float* score_w = (const float*)d_in[15];
    const float* score_b = (const float*)d_in[16];
    float* ws  = (float*)d_ws;
    float* out = (float*)d_out;

    // zero the software grid-barrier counter (graph-capturable async memset)
    hipMemsetAsync((char*)d_ws + (size_t)OFF_BAR * sizeof(float), 0, 64, stream);

    k_gemm<<<dim3(8, 64, 2), 256, 0, stream>>>(enc, attn_wm, hop_wm, ws);

    k_steps<<<NBLK, NTHR, 0, stream>>>(enc, mask, attn_wq, attn_v, hop_wq, hop_v,
                                       init_h, init_c, init_i, w_ih, w_hh, b_ih,
                                       b_hh, score_w, score_b, ws, out);
}

// Round 6
// 2146.064 us; speedup vs baseline: 1.3194x; 1.0040x over previous
//
#include <hip/hip_runtime.h>
#include <hip/hip_bf16.h>

// Problem constants (reference: N=8192, D=H=1024, NSTEP=8)
#define NN 8192
#define HH 1024
#define NSTEP 8
#define NBLK 256
#define NTHR 512

// ---- workspace layout (float offsets) ----
#define OFF_ATTN   0                     // attn_feat [8192*1024]
#define OFF_HOP    8388608               // hop_feat  [8192*1024]
#define B2         16777216
#define OFF_NEG    (B2 + 0)              // [8192]
#define OFF_SEL    (B2 + 8192)           // [8192]
#define OFF_H      (B2 + 16384)          // h[parity][chain][1024]
#define OFF_C      (B2 + 20480)          // c[parity][chain][1024]
#define OFF_QW     (B2 + 24576)          // qw[chain][1024]
#define OFF_QW2    (B2 + 26624)          // qw2[chain][1024]
#define OFF_GCTXA  (B2 + 28672)          // glimpse ctx actor  [1024] (atomic accum)
#define OFF_GCTXC  (B2 + 29696)          // glimpse ctx critic [1024]
#define OFF_ACTX   (B2 + 30720)          // critic attn ctx    [1024]
#define OFF_GLA    (B2 + 31744)          // glimpse l actor (scalar)
#define OFF_GLC    (B2 + 31745)          // glimpse l critic
#define OFF_AL     (B2 + 31746)          // critic attn l
#define OFF_AMAX   (B2 + 31748)          // packed u64 argmax (8B aligned)
#define OFF_BAR    (B2 + 31752)          // barrier counter (uint)

__device__ __forceinline__ float sigmoidf_(float x) {
    return 1.0f / (1.0f + __expf(-x));
}
__device__ __forceinline__ float tanhf_(float x) {
    float e = __expf(2.0f * x);
    return 1.0f - 2.0f / (e + 1.0f);
}

__device__ __forceinline__ float score16(const float4* f, const float4* q, const float4* v) {
    float s = 0.0f;
#pragma unroll
    for (int j = 0; j < 4; j++) {
        s += tanhf_(f[j].x + q[j].x) * v[j].x;
        s += tanhf_(f[j].y + q[j].y) * v[j].y;
        s += tanhf_(f[j].z + q[j].z) * v[j].z;
        s += tanhf_(f[j].w + q[j].w) * v[j].w;
    }
    return s;
}

// software grid barrier: release arrival, RELAXED spin (no cache ops in loop),
// single acquire fence on exit. Avoids per-poll L1/L2 invalidation.
__device__ __forceinline__ void gsync(unsigned int* bar, unsigned int target) {
    __syncthreads();
    if (threadIdx.x == 0) {
        __hip_atomic_fetch_add(bar, 1u, __ATOMIC_RELEASE, __HIP_MEMORY_SCOPE_AGENT);
        while (__hip_atomic_load(bar, __ATOMIC_RELAXED, __HIP_MEMORY_SCOPE_AGENT) < target)
            __builtin_amdgcn_s_sleep(2);
    }
    __syncthreads();
    __builtin_amdgcn_fence(__ATOMIC_ACQUIRE, "agent");
}

// monotone orderable key for fp32 + first-index tie-break
__device__ __forceinline__ unsigned long long packscore(float f, int i) {
    unsigned int u = __float_as_uint(f);
    unsigned int key = (u & 0x80000000u) ? ~u : (u | 0x80000000u);
    return ((unsigned long long)key << 32) | (unsigned int)(0x7FFFFFFF - i);
}

// ---------------- GEMM: feats = enc @ {attn_wm, hop_wm}, 128x128 tile, 8x8/thread ----------------
// split microtile {c*4, c*4+64}: LDS reads are 2-way conflicted only (free per m136)
__global__ __launch_bounds__(256, 4) void k_gemm(const float* __restrict__ A,
                                                 const float* __restrict__ W0,
                                                 const float* __restrict__ W1,
                                                 float* __restrict__ ws) {
    const float* B = blockIdx.z ? W1 : W0;
    float* Cout = ws + (blockIdx.z ? OFF_HOP : OFF_ATTN);
    const int rowbase = blockIdx.y * 128;
    const int colbase = blockIdx.x * 128;
    __shared__ float As[16][132];
    __shared__ float Bs[16][132];
    const int t  = threadIdx.x;
    const int tx = t & 15;
    const int ty2 = t >> 4;  // 0..15
    const int ar = t >> 1, aks = (t & 1) * 8;
    const int bk = t >> 4, bc = (t & 15) * 8;
    float acc[8][8] = {};
    for (int kk = 0; kk < 1024; kk += 16) {
        float4 a0 = *(const float4*)&A[(size_t)(rowbase + ar) * 1024 + kk + aks];
        float4 a1 = *(const float4*)&A[(size_t)(rowbase + ar) * 1024 + kk + aks + 4];
        float4 b0 = *(const float4*)&B[(size_t)(kk + bk) * 1024 + colbase + bc];
        float4 b1 = *(const float4*)&B[(size_t)(kk + bk) * 1024 + colbase + bc + 4];
        __syncthreads();
        As[aks + 0][ar] = a0.x; As[aks + 1][ar] = a0.y;
        As[aks + 2][ar] = a0.z; As[aks + 3][ar] = a0.w;
        As[aks + 4][ar] = a1.x; As[aks + 5][ar] = a1.y;
        As[aks + 6][ar] = a1.z; As[aks + 7][ar] = a1.w;
        *(float4*)&Bs[bk][bc]     = b0;
        *(float4*)&Bs[bk][bc + 4] = b1;
        __syncthreads();
#pragma unroll
        for (int k = 0; k < 16; k++) {
            float4 x0 = *(const float4*)&As[k][ty2 * 4];
            float4 x1 = *(const float4*)&As[k][ty2 * 4 + 64];
            float4 y0 = *(const float4*)&Bs[k][tx * 4];
            float4 y1 = *(const float4*)&Bs[k][tx * 4 + 64];
            float xa[8] = {x0.x, x0.y, x0.z, x0.w, x1.x, x1.y, x1.z, x1.w};
            float yb[8] = {y0.x, y0.y, y0.z, y0.w, y1.x, y1.y, y1.z, y1.w};
#pragma unroll
            for (int i = 0; i < 8; i++)
#pragma unroll
                for (int j = 0; j < 8; j++)
                    acc[i][j] += xa[i] * yb[j];
        }
    }
#pragma unroll
    for (int i = 0; i < 8; i++) {
        int row = rowbase + ((i < 4) ? (ty2 * 4 + i) : (64 + ty2 * 4 + (i - 4)));
        float* cr = &Cout[(size_t)row * 1024 + colbase];
        *(float4*)&cr[tx * 4]      = make_float4(acc[i][0], acc[i][1], acc[i][2], acc[i][3]);
        *(float4*)&cr[64 + tx * 4] = make_float4(acc[i][4], acc[i][5], acc[i][6], acc[i][7]);
    }
}

// ---------------- persistent fused 8-step decode ----------------
// grid 256 x block 512, 1 block/CU; lane chunk mapping: cols {lane*4 + p*256}
__global__ __launch_bounds__(512) void k_steps(
        const float* __restrict__ enc, const int* __restrict__ mask,
        const float* __restrict__ attn_wq, const float* __restrict__ attn_v,
        const float* __restrict__ hop_wq, const float* __restrict__ hop_v,
        const float* __restrict__ init_h, const float* __restrict__ init_c,
        const float* __restrict__ init_i,
        const float* __restrict__ w_ih, const float* __restrict__ w_hh,
        const float* __restrict__ b_ih, const float* __restrict__ b_hh,
        const float* __restrict__ score_w, const float* __restrict__ score_b,
        float* __restrict__ ws, float* __restrict__ out) {
    const int b = blockIdx.x;
    const int t = threadIdx.x;
    const int w = t >> 6, lane = t & 63;
    __shared__ __align__(16) float smem[8224];
    unsigned int* bar = (unsigned int*)(ws + OFF_BAR);
    unsigned int bt = 0;

    // ---- phase 0: init ----
    {
        int i = b * NTHR + t;
        if (i < NN) {
            ws[OFF_NEG + i] = (mask[i] == 0) ? -1e8f : 0.0f;
            ws[OFF_SEL + i] = 0.0f;
        }
        if (i < 2048) {  // parity-0 h,c for both chains
            ws[OFF_H + i] = init_h[i & 1023];
            ws[OFF_C + i] = init_c[i & 1023];
        }
        if (b == 16) {  // zero atomic accumulators
            for (int c = t; c < 1024; c += NTHR) {
                ws[OFF_GCTXA + c] = 0.0f;
                ws[OFF_GCTXC + c] = 0.0f;
                ws[OFF_ACTX + c]  = 0.0f;
            }
            if (t == 0) {
                ws[OFF_GLA] = 0.0f; ws[OFF_GLC] = 0.0f; ws[OFF_AL] = 0.0f;
                *(unsigned long long*)&ws[OFF_AMAX] = 0ull;
            }
        }
    }
    bt += NBLK; gsync(bar, bt);

    for (int step = 0; step < NSTEP; step++) {
        const int par = step & 1;
        // ===== P1: finalize prev step (block 0) + LSTM both chains =====
        {
            int besti = 0;
            float rinv = 0.0f;
            if (step > 0) {
                unsigned long long pk = *(const unsigned long long*)&ws[OFF_AMAX];
                besti = 0x7FFFFFFF - (int)(unsigned int)(pk & 0xFFFFFFFFull);
                rinv = 1.0f / ws[OFF_AL];
            }
            if (step > 0 && b == 0) {
                float p = ws[OFF_ACTX + t] * rinv * score_w[t]
                        + ws[OFF_ACTX + t + 512] * rinv * score_w[t + 512];
#pragma unroll
                for (int off = 32; off; off >>= 1) p += __shfl_down(p, off);
                if (lane == 0) smem[8192 + w] = p;
                __syncthreads();
                if (t == 0) {
                    float s = 0.0f;
#pragma unroll
                    for (int ww = 0; ww < 8; ww++) s += smem[8192 + ww];
                    out[8 + NSTEP * 1024 + (step - 1)] = s + score_b[0];
                    out[step - 1] = (float)besti;
                    ws[OFF_SEL + besti] = -1e18f;
                }
                __syncthreads();
            }
            const int gw = b * 8 + w;
            if (gw < 1024) {
                const int j = gw;
                float4 xa[4], xc[4], ha[4], hc[4];
#pragma unroll
                for (int p = 0; p < 4; p++) {
                    int kk = lane * 4 + p * 256;
                    if (step == 0) {
                        xa[p] = *(const float4*)&init_i[kk];
                        xc[p] = xa[p];
                    } else {
                        xa[p] = *(const float4*)&enc[(size_t)besti * 1024 + kk];
                        float4 cx = *(const float4*)&ws[OFF_ACTX + kk];
                        xc[p] = make_float4(cx.x * rinv, cx.y * rinv, cx.z * rinv, cx.w * rinv);
                    }
                    ha[p] = *(const float4*)&ws[OFF_H + par * 2048 + kk];
                    hc[p] = *(const float4*)&ws[OFF_H + par * 2048 + 1024 + kk];
                }
                float pa[4], pc[4];
#pragma unroll
                for (int g = 0; g < 4; g++) {
                    const float* wi = w_ih + (size_t)(g * 1024 + j) * 1024;
                    const float* wh = w_hh + (size_t)(g * 1024 + j) * 1024;
                    float sa = 0.0f, sc = 0.0f;
#pragma unroll
                    for (int p = 0; p < 4; p++) {
                        int kk = lane * 4 + p * 256;
                        float4 a = *(const float4*)&wi[kk];
                        float4 hh = *(const float4*)&wh[kk];
                        sa += a.x * xa[p].x + a.y * xa[p].y + a.z * xa[p].z + a.w * xa[p].w
                            + hh.x * ha[p].x + hh.y * ha[p].y + hh.z * ha[p].z + hh.w * ha[p].w;
                        sc += a.x * xc[p].x + a.y * xc[p].y + a.z * xc[p].z + a.w * xc[p].w
                            + hh.x * hc[p].x + hh.y * hc[p].y + hh.z * hc[p].z + hh.w * hc[p].w;
                    }
                    pa[g] = sa; pc[g] = sc;
                }
#pragma unroll
                for (int off = 1; off < 64; off <<= 1) {
#pragma unroll
                    for (int g = 0; g < 4; g++) {
                        pa[g] += __shfl_xor(pa[g], off);
                        pc[g] += __shfl_xor(pc[g], off);
                    }
                }
                if (lane == 0) {
                    float bb0 = b_ih[j] + b_hh[j];
                    float bb1 = b_ih[1024 + j] + b_hh[1024 + j];
                    float bb2 = b_ih[2048 + j] + b_hh[2048 + j];
                    float bb3 = b_ih[3072 + j] + b_hh[3072 + j];
                    {
                        float ig = sigmoidf_(pa[0] + bb0), fg = sigmoidf_(pa[1] + bb1);
                        float gg = tanhf_(pa[2] + bb2),   og = sigmoidf_(pa[3] + bb3);
                        float cv = fg * ws[OFF_C + par * 2048 + j] + ig * gg;
                        ws[OFF_H + (par ^ 1) * 2048 + j] = og * tanhf_(cv);
                        ws[OFF_C + (par ^ 1) * 2048 + j] = cv;
                    }
                    {
                        float ig = sigmoidf_(pc[0] + bb0), fg = sigmoidf_(pc[1] + bb1);
                        float gg = tanhf_(pc[2] + bb2),   og = sigmoidf_(pc[3] + bb3);
                        float cv = fg * ws[OFF_C + par * 2048 + 1024 + j] + ig * gg;
                        ws[OFF_H + (par ^ 1) * 2048 + 1024 + j] = og * tanhf_(cv);
                        ws[OFF_C + (par ^ 1) * 2048 + 1024 + j] = cv;
                    }
                }
            }
        }
        bt += NBLK; gsync(bar, bt);

        // ===== P2: qw = h' @ hop_wq (blocks 0..31); block 32 zeroes attn accums =====
        if (b < 32) {
            const int chain = b >> 4, kb = b & 15;
            const float* hsrc = ws + OFF_H + (par ^ 1) * 2048 + chain * 1024;
            smem[t]       = hsrc[t];
            smem[t + 512] = hsrc[t + 512];
            __syncthreads();
            const int col = kb * 64 + (t & 63);
            const int jg = t >> 6;
            const float* wq = hop_wq + (size_t)jg * 128 * 1024 + col;
            float acc = 0.0f;
#pragma unroll 8
            for (int j = 0; j < 128; j++) acc += smem[jg * 128 + j] * wq[(size_t)j * 1024];
            smem[1024 + t] = acc;
            __syncthreads();
            if (t < 64) {
                float s = 0.0f;
#pragma unroll
                for (int jg2 = 0; jg2 < 8; jg2++) s += smem[1024 + jg2 * 64 + t];
                ws[OFF_QW + chain * 1024 + kb * 64 + t] = s;
            }
        } else if (b == 32) {
            for (int c = t; c < 1024; c += NTHR) ws[OFF_ACTX + c] = 0.0f;
            if (t == 0) {
                ws[OFF_AL] = 0.0f;
                *(unsigned long long*)&ws[OFF_AMAX] = 0ull;
            }
        }
        bt += NBLK; gsync(bar, bt);

        // ===== P3: glimpse pass over hop_feat (both chains), fixed-max softmax =====
        {
            float4 qa[4], qc[4], v4[4];
#pragma unroll
            for (int p = 0; p < 4; p++) {
                int kk = lane * 4 + p * 256;
                qa[p] = *(const float4*)&ws[OFF_QW + kk];
                qc[p] = *(const float4*)&ws[OFF_QW + 1024 + kk];
                v4[p] = *(const float4*)&hop_v[kk];
            }
            float la = 0.0f, lc = 0.0f;
            float4 ca[4] = {}, cc[4] = {};
            for (int i = b * 8 + w; i < NN; i += 2048) {
                const float* row = ws + OFF_HOP + (size_t)i * 1024;
                float4 f[4];
#pragma unroll
                for (int p = 0; p < 4; p++) f[p] = *(const float4*)&row[lane * 4 + p * 256];
                float sa = score16(f, qa, v4);
                float sc = score16(f, qc, v4);
#pragma unroll
                for (int off = 1; off < 64; off <<= 1) {
                    sa += __shfl_xor(sa, off);
                    sc += __shfl_xor(sc, off);
                }
                float ng = ws[OFF_NEG + i];
                float ea = __expf(sa + ng), ec = __expf(sc + ng);
                la += ea; lc += ec;
#pragma unroll
                for (int p = 0; p < 4; p++) {
                    ca[p].x += ea * f[p].x; ca[p].y += ea * f[p].y;
                    ca[p].z += ea * f[p].z; ca[p].w += ea * f[p].w;
                    cc[p].x += ec * f[p].x; cc[p].y += ec * f[p].y;
                    cc[p].z += ec * f[p].z; cc[p].w += ec * f[p].w;
                }
            }
            // block reduce + atomic accumulate: actor
            if (lane == 0) smem[8192 + w] = la;
#pragma unroll
            for (int p = 0; p < 4; p++) *(float4*)&smem[w * 1024 + lane * 4 + p * 256] = ca[p];
            __syncthreads();
            {
                const int k = t * 2;
                float s0 = 0.0f, s1 = 0.0f;
#pragma unroll
                for (int ww = 0; ww < 8; ww++) {
                    s0 += smem[ww * 1024 + k];
                    s1 += smem[ww * 1024 + k + 1];
                }
                atomicAdd(&ws[OFF_GCTXA + k], s0);
                atomicAdd(&ws[OFF_GCTXA + k + 1], s1);
                if (t == 0) {
                    float s = 0.0f;
#pragma unroll
                    for (int ww = 0; ww < 8; ww++) s += smem[8192 + ww];
                    atomicAdd(&ws[OFF_GLA], s);
                }
            }
            __syncthreads();
            // critic
            if (lane == 0) smem[8192 + w] = lc;
#pragma unroll
            for (int p = 0; p < 4; p++) *(float4*)&smem[w * 1024 + lane * 4 + p * 256] = cc[p];
            __syncthreads();
            {
                const int k = t * 2;
                float s0 = 0.0f, s1 = 0.0f;
#pragma unroll
                for (int ww = 0; ww < 8; ww++) {
                    s0 += smem[ww * 1024 + k];
                    s1 += smem[ww * 1024 + k + 1];
                }
                atomicAdd(&ws[OFF_GCTXC + k], s0);
                atomicAdd(&ws[OFF_GCTXC + k + 1], s1);
                if (t == 0) {
                    float s = 0.0f;
#pragma unroll
                    for (int ww = 0; ww < 8; ww++) s += smem[8192 + ww];
                    atomicAdd(&ws[OFF_GLC], s);
                }
            }
            __syncthreads();
        }
        bt += NBLK; gsync(bar, bt);

        // ===== P4: q = ctx/l; qw2 = q @ attn_wq (blocks 0..31); states out (block 0) =====
        if (b < 32) {
            const int chain = b >> 4, kb = b & 15;
            const float linv = 1.0f / ws[chain ? OFF_GLC : OFF_GLA];
            const float* gc = ws + (chain ? OFF_GCTXC : OFF_GCTXA);
            smem[t * 2]     = gc[t * 2] * linv;
            smem[t * 2 + 1] = gc[t * 2 + 1] * linv;
            __syncthreads();
            if (b == 0) {
                out[8 + step * 1024 + t * 2]     = smem[t * 2];
                out[8 + step * 1024 + t * 2 + 1] = smem[t * 2 + 1];
            }
            const int col = kb * 64 + (t & 63);
            const int jg = t >> 6;
            const float* aw = attn_wq + (size_t)jg * 128 * 1024 + col;
            float acc = 0.0f;
#pragma unroll 8
            for (int j = 0; j < 128; j++) acc += smem[jg * 128 + j] * aw[(size_t)j * 1024];
            __syncthreads();
            smem[1024 + t] = acc;
            __syncthreads();
            if (t < 64) {
                float s = 0.0f;
#pragma unroll
                for (int jg2 = 0; jg2 < 8; jg2++) s += smem[1024 + jg2 * 64 + t];
                ws[OFF_QW2 + chain * 1024 + kb * 64 + t] = s;
            }
        }
        bt += NBLK; gsync(bar, bt);

        // ===== P5: attn pass — actor argmax + critic ctx over enc; block 0 zeroes glimpse accums =====
        {
            if (b == 0) {
                for (int c = t; c < 1024; c += NTHR) {
                    ws[OFF_GCTXA + c] = 0.0f;
                    ws[OFF_GCTXC + c] = 0.0f;
                }
                if (t == 0) { ws[OFF_GLA] = 0.0f; ws[OFF_GLC] = 0.0f; }
            }
            float4 qa[4], qc[4], v4[4];
#pragma unroll
            for (int p = 0; p < 4; p++) {
                int kk = lane * 4 + p * 256;
                qa[p] = *(const float4*)&ws[OFF_QW2 + kk];
                qc[p] = *(const float4*)&ws[OFF_QW2 + 1024 + kk];
                v4[p] = *(const float4*)&attn_v[kk];
            }
            float bm = -1e30f;
            int bi = 0;
            float lc = 0.0f;
            float4 cc[4] = {};
            for (int i = b * 8 + w; i < NN; i += 2048) {
                const float* frow = ws + OFF_ATTN + (size_t)i * 1024;
                const float* erow = enc + (size_t)i * 1024;
                float4 f[4], e[4];
#pragma unroll
                for (int p = 0; p < 4; p++) {
                    f[p] = *(const float4*)&frow[lane * 4 + p * 256];
                    e[p] = *(const float4*)&erow[lane * 4 + p * 256];
                }
                float sa = score16(f, qa, v4);
                float sc = score16(f, qc, v4);
#pragma unroll
                for (int off = 1; off < 64; off <<= 1) {
                    sa += __shfl_xor(sa, off);
                    sc += __shfl_xor(sc, off);
                }
                float ng = ws[OFF_NEG + i];
                float Sa = sa + ng + ws[OFF_SEL + i];
                if (Sa > bm) { bm = Sa; bi = i; }
                float ec = __expf(sc + ng);
                lc += ec;
#pragma unroll
                for (int p = 0; p < 4; p++) {
                    cc[p].x += ec * e[p].x; cc[p].y += ec * e[p].y;
                    cc[p].z += ec * e[p].z; cc[p].w += ec * e[p].w;
                }
            }
            unsigned long long* spk = (unsigned long long*)(smem + 8200);
            if (lane == 0) { smem[8192 + w] = lc; spk[w] = packscore(bm, bi); }
#pragma unroll
            for (int p = 0; p < 4; p++) *(float4*)&smem[w * 1024 + lane * 4 + p * 256] = cc[p];
            __syncthreads();
            {
                const int k = t * 2;
                float s0 = 0.0f, s1 = 0.0f;
#pragma unroll
                for (int ww = 0; ww < 8; ww++) {
                    s0 += smem[ww * 1024 + k];
                    s1 += smem[ww * 1024 + k + 1];
                }
                atomicAdd(&ws[OFF_ACTX + k], s0);
                atomicAdd(&ws[OFF_ACTX + k + 1], s1);
                if (t == 0) {
                    float s = 0.0f;
                    unsigned long long mx = 0ull;
#pragma unroll
                    for (int ww = 0; ww < 8; ww++) {
                        s += smem[8192 + ww];
                        if (spk[ww] > mx) mx = spk[ww];
                    }
                    atomicAdd(&ws[OFF_AL], s);
                    atomicMax((unsigned long long*)&ws[OFF_AMAX], mx);
                }
            }
            __syncthreads();
        }
        bt += NBLK; gsync(bar, bt);
    }

    // ===== epilogue: finalize step 7 (block 0) =====
    if (b == 0) {
        unsigned long long pk = *(const unsigned long long*)&ws[OFF_AMAX];
        int besti = 0x7FFFFFFF - (int)(unsigned int)(pk & 0xFFFFFFFFull);
        float rinv = 1.0f / ws[OFF_AL];
        float p = ws[OFF_ACTX + t] * rinv * score_w[t]
                + ws[OFF_ACTX + t + 512] * rinv * score_w[t + 512];
#pragma unroll
        for (int off = 32; off; off >>= 1) p += __shfl_down(p, off);
        if (lane == 0) smem[8192 + w] = p;
        __syncthreads();
        if (t == 0) {
            float s = 0.0f;
#pragma unroll
            for (int ww = 0; ww < 8; ww++) s += smem[8192 + ww];
            out[8 + NSTEP * 1024 + (NSTEP - 1)] = s + score_b[0];
            out[NSTEP - 1] = (float)besti;
        }
    }
}

extern "C" void kernel_launch(void* const* d_in, const int* in_sizes, int n_in,
                              void* d_out, int out_size, void* d_ws, size_t ws_size,
                              hipStream_t stream) {
    const float* enc     = (const float*)d_in[0];
    const int*   mask    = (const int*)d_in[1];
    const float* attn_wm = (const float*)d_in[2];
    const float* attn_wq = (const float*)d_in[3];
    const float* attn_v  = (const float*)d_in[4];
    const float* hop_wm  = (const float*)d_in[5];
    const float* hop_wq  = (const float*)d_in[6];
    const float* hop_v   = (const float*)d_in[7];
    const float* init_i  = (const float*)d_in[8];
    const float* init_h  = (const float*)d_in[9];
    const float* init_c  = (const float*)d_in[10];
    const float* w_ih    = (const float*)d_in[11];
    const float* w_hh    = (const float*)d_in[12];
    const float* b_ih    = (const float*)d_in[13];
    const float* b_hh    = (const float*)d_in[14];
    const float* score_w = (const float*)d_in[15];
    const float* score_b = (const float*)d_in[16];
    float* ws  = (float*)d_ws;
    float* out = (float*)d_out;

    // zero the software grid-barrier counter (graph-capturable async memset)
    (void)hipMemsetAsync((char*)d_ws + (size_t)OFF_BAR * sizeof(float), 0, 64, stream);

    k_gemm<<<dim3(8, 64, 2), 256, 0, stream>>>(enc, attn_wm, hop_wm, ws);

    k_steps<<<NBLK, NTHR, 0, stream>>>(enc, mask, attn_wq, attn_v, hop_wq, hop_v,
                                       init_h, init_c, init_i, w_ih, w_hh, b_ih,
                                       b_hh, score_w, score_b, ws, out);
}